// Round 13
// baseline (322.013 us; speedup 1.0000x reference)
//
#include <hip/hip_runtime.h>
#include <stdint.h>

#define DEV __device__ __forceinline__

typedef __attribute__((ext_vector_type(4))) float f32x4;
typedef __attribute__((ext_vector_type(16))) float f32x16;
typedef __attribute__((ext_vector_type(8))) __bf16 bf16x8;
typedef __attribute__((ext_vector_type(4))) __bf16 bf16x4;
typedef __attribute__((ext_vector_type(8))) short short8;
typedef __attribute__((ext_vector_type(4))) unsigned short u16x4;

DEV unsigned short f2bf_n(float f) {             // native cvt (RNE, 1 op)
    __bf16 h = (__bf16)f;
    return __builtin_bit_cast(unsigned short, h);
}
DEV bf16x8 ld8(const unsigned short* p) {        // 16B vector load (LDS or global)
    short8 v = *(const short8*)p;
    return __builtin_bit_cast(bf16x8, v);
}
// async global->LDS DMA, 16B per lane. lds base wave-uniform; HW adds lane*16.
DEV void ldsdma16(unsigned short* lds, const unsigned short* g) {
    __builtin_amdgcn_global_load_lds(
        (const __attribute__((address_space(1))) unsigned int*)g,
        (__attribute__((address_space(3))) unsigned int*)lds, 16, 0, 0);
}

// ---------------------------------------------------------------------------
// Pre-convert f32 -> bf16: X (4.19M el) then Wq|Wk|Wv|Wo (1.05M each).
// ---------------------------------------------------------------------------
__global__ __launch_bounds__(256) void conv_kernel(
    const float* __restrict__ X,
    const float* __restrict__ Wq, const float* __restrict__ Wk,
    const float* __restrict__ Wv, const float* __restrict__ Wo,
    unsigned short* __restrict__ Xb, unsigned short* __restrict__ Wb)
{
    int c = blockIdx.x * 256 + threadIdx.x;      // chunk of 4 floats
    const float* src;
    unsigned short* dst;
    if (c < 1048576) {
        src = X + c * 4; dst = Xb + c * 4;
    } else {
        int c2 = c - 1048576;
        int wsel = c2 >> 18;
        int off = (c2 & 262143) * 4;
        const float* ws_[4] = { Wq, Wk, Wv, Wo };
        src = ws_[wsel] + off;
        dst = Wb + wsel * 1048576 + off;
    }
    f32x4 v = *(const f32x4*)src;
    bf16x4 b = { (__bf16)v[0], (__bf16)v[1], (__bf16)v[2], (__bf16)v[3] };
    *(bf16x4*)dst = b;
}

// ---------------------------------------------------------------------------
// Fused QKV projection — round-8 structure (BK=64 single-buffer DMA staging).
// grid (32, 24). All epilogues repack via LDS -> coalesced 16B stores.
// ---------------------------------------------------------------------------
__global__ __launch_bounds__(256) void qkv_kernel(
    const unsigned short* __restrict__ Xb, const unsigned short* __restrict__ Wb,
    const float* __restrict__ bq, const float* __restrict__ bk,
    const float* __restrict__ bv,
    unsigned short* __restrict__ Qws, unsigned short* __restrict__ Kws,
    unsigned short* __restrict__ VT)
{
    __shared__ __align__(16) unsigned short SMEM[17408];
    unsigned short* As = SMEM;
    unsigned short* Bs = SMEM + 8192;

    const int t = threadIdx.x;
    const int lane = t & 63, w = t >> 6;
    const int wm = w & 1, wn = w >> 1;
    const int l15 = lane & 15, grp = lane >> 4;
    const int m0 = blockIdx.x * 128;
    const int which = blockIdx.y >> 3;
    const int e0 = (blockIdx.y & 7) * 128;

    const unsigned short* Wmat = Wb + which * 1048576;
    const float* bias = (which == 0) ? bq : (which == 1) ? bk : bv;

    const int srow = lane >> 3;
    const int sc_  = lane & 7;

    f32x4 acc[4][4];
#pragma unroll
    for (int i = 0; i < 4; ++i)
#pragma unroll
        for (int j = 0; j < 4; ++j) acc[i][j] = (f32x4){0.f, 0.f, 0.f, 0.f};

    for (int kt = 0; kt < 16; ++kt) {
        const int k0 = kt * 64;
        __syncthreads();
#pragma unroll
        for (int j = 0; j < 4; ++j) {
            int row = (w * 4 + j) * 8 + srow;
            int cs = sc_ ^ (row & 7);
            ldsdma16(&As[(w * 4 + j) * 512],
                     &Xb[(m0 + row) * 1024 + k0 + cs * 8]);
            ldsdma16(&Bs[(w * 4 + j) * 512],
                     &Wmat[(e0 + row) * 1024 + k0 + cs * 8]);
        }
        __syncthreads();
#pragma unroll
        for (int kk = 0; kk < 64; kk += 32) {
            const int cb = kk >> 3;
            bf16x8 af[4], bfr[4];
#pragma unroll
            for (int i = 0; i < 4; ++i) {
                int r = wm * 64 + i * 16 + l15;
                af[i] = ld8(&As[r * 64 + (((cb + grp) ^ (r & 7)) << 3)]);
            }
#pragma unroll
            for (int j = 0; j < 4; ++j) {
                int r = wn * 64 + j * 16 + l15;
                bfr[j] = ld8(&Bs[r * 64 + (((cb + grp) ^ (r & 7)) << 3)]);
            }
#pragma unroll
            for (int i = 0; i < 4; ++i)
#pragma unroll
                for (int j = 0; j < 4; ++j)
                    acc[i][j] = __builtin_amdgcn_mfma_f32_16x16x32_bf16(
                        af[i], bfr[j], acc[i][j], 0, 0, 0);
        }
    }

    __syncthreads();
    const int b = m0 >> 11;

    if (which == 2) {
#pragma unroll
        for (int j = 0; j < 4; ++j) {
            int e = e0 + wn * 64 + j * 16 + l15;
            float bv_ = bias[e];
#pragma unroll
            for (int i = 0; i < 4; ++i) {
                u16x4 pk;
#pragma unroll
                for (int r = 0; r < 4; ++r) pk[r] = f2bf_n(acc[i][j][r] + bv_);
                *(u16x4*)&SMEM[(wn * 64 + j * 16 + l15) * 136 +
                               wm * 64 + i * 16 + grp * 4] = pk;
            }
        }
        __syncthreads();
        const int s0 = m0 & 2047;
#pragma unroll
        for (int round = 0; round < 8; ++round) {
            int dhl = (t >> 4) + round * 16;
            int chunk = t & 15;
            int h = (e0 + dhl) >> 6, dh = (e0 + dhl) & 63;
            *(short8*)&VT[((b * 16 + h) * 64 + dh) * 2048 + s0 + chunk * 8] =
                *(const short8*)&SMEM[dhl * 136 + chunk * 8];
        }
    } else {
        const float scale = (which == 0) ? 0.125f : 1.0f;
#pragma unroll
        for (int j = 0; j < 4; ++j) {
            int e = e0 + wn * 64 + j * 16 + l15;
            float bv_ = bias[e];
#pragma unroll
            for (int i = 0; i < 4; ++i)
#pragma unroll
                for (int r = 0; r < 4; ++r)
                    SMEM[(wm * 64 + i * 16 + grp * 4 + r) * 136 +
                         wn * 64 + j * 16 + l15] =
                        f2bf_n((acc[i][j][r] + bv_) * scale);
        }
        __syncthreads();
        unsigned short* dst = (which == 0) ? Qws : Kws;
#pragma unroll
        for (int round = 0; round < 8; ++round) {
            int tl = (t >> 4) + round * 16;
            int chunk = t & 15;
            int e = e0 + chunk * 8;
            int h = e >> 6, dh = e & 63;
            int s = (m0 & 2047) + tl;
            *(short8*)&dst[((b * 16 + h) * 2048 + s) * 64 + dh] =
                *(const short8*)&SMEM[tl * 136 + chunk * 8];
        }
    }
}

// ---------------------------------------------------------------------------
// Flash attention v6: 32x32x16 + FOUR-way split-K, 64 q-rows/block.
// grid (32, 32) = 1024 blocks, 512 thr (8 waves = 2 qg x 4 ksub).
// Each kb stages 128 keys; wave (qg,ksub) handles keys [ksub*32, ksub*32+32)
// for its 32 q-rows. LDS = 53,248 B -> 3 blocks/CU; grid now supplies them
// (round 12's shrink was grid-capped at 2). Merge: staged 2-round LDS tree.
// ---------------------------------------------------------------------------
__global__ __launch_bounds__(512, 6) void attn_kernel(
    const unsigned short* __restrict__ Qws, const unsigned short* __restrict__ Kws,
    const unsigned short* __restrict__ VT, const float* __restrict__ mask,
    unsigned short* __restrict__ Xattn)
{
    // Ks 128x64 (8192 el) | Vs 64x128 (8192 el) | Ps 8 x 32x40 (10240 el)
    __shared__ __align__(16) unsigned short SMEM[26624];   // 53,248 B
    unsigned short* Ks = SMEM;                    // [key][dh],  8-chunk swizzle
    unsigned short* Vs = SMEM + 8192;             // [dh][key], 16-chunk swizzle
    unsigned short* Ps = SMEM + 16384;            // per-wave 32x40 strips
    float* mrg = (float*)SMEM;                    // merge overlay (<= 49,152 B)

    const int t = threadIdx.x;
    const int lane = t & 63, w = t >> 6;          // 8 waves
    const int l31 = lane & 31, half = lane >> 5;
    const int qg = w & 1, ksub = w >> 1;          // 2 q-groups x 4 key-subsets
    const int q0 = blockIdx.x * 64;
    const int bh = blockIdx.y;
    const int b = bh >> 4;

    const unsigned short* Kp = Kws + (size_t)bh * 131072;  // [key][dh]
    const unsigned short* Vp = VT  + (size_t)bh * 131072;  // [dh][key]

    // Q A-frags (persistent): A[m=l31][k=half*8+j] per 16-k step
    bf16x8 qf[4];
#pragma unroll
    for (int s = 0; s < 4; ++s)
        qf[s] = ld8(&Qws[(bh * 2048 + q0 + qg * 32 + l31) * 64 + s * 16 + half * 8]);

    // ones B-frag: B[n][k]=1 iff n==0
    short onev = (l31 == 0) ? (short)0x3F80 : (short)0;
    short8 ov = { onev, onev, onev, onev, onev, onev, onev, onev };
    bf16x8 ones_f = __builtin_bit_cast(bf16x8, ov);

    unsigned short* Pw = Ps + w * 1280;           // this wave's 32x40 strip

    f32x16 accd[2], accl;
#pragma unroll
    for (int d = 0; d < 2; ++d)
#pragma unroll
        for (int r = 0; r < 16; ++r) accd[d][r] = 0.f;
#pragma unroll
    for (int r = 0; r < 16; ++r) accl[r] = 0.f;

    for (int kb = 0; kb < 16; ++kb) {
        const int k0 = kb * 128;
        __syncthreads();                 // prev tile's readers done
#pragma unroll
        for (int ii = 0; ii < 2; ++ii) { // Ks: 16 DMA (8 rows x 128B), 2/wave
            int inst = w * 2 + ii;
            int row = inst * 8 + (lane >> 3);
            int cs = (lane & 7) ^ (row & 7);
            ldsdma16(&Ks[inst * 512], &Kp[(k0 + row) * 64 + cs * 8]);
        }
#pragma unroll
        for (int ii = 0; ii < 2; ++ii) { // Vs: 16 DMA (4 rows x 256B), 2/wave
            int inst = w * 2 + ii;
            int row = inst * 4 + (lane >> 4);
            int cs = (lane & 15) ^ (row & 15);
            ldsdma16(&Vs[inst * 512], &Vp[row * 2048 + k0 + cs * 8]);
        }
        float mc = mask[b * 2048 + k0 + ksub * 32 + l31];
        __syncthreads();                 // DMA drained

        // S = Q.K^T over this wave's 32 keys
        f32x16 z;
#pragma unroll
        for (int r = 0; r < 16; ++r) z[r] = 0.f;
        int rK = ksub * 32 + l31;
#pragma unroll
        for (int s = 0; s < 4; ++s) {
            int chunk = s * 2 + half;
            bf16x8 kf = ld8(&Ks[rK * 64 + ((chunk ^ (rK & 7)) << 3)]);
            z = __builtin_amdgcn_mfma_f32_32x32x16_bf16(qf[s], kf, z, 0, 0, 0);
        }
        // P = exp(s)*m into wave-private strip (col = l31)
#pragma unroll
        for (int r = 0; r < 16; ++r) {
            float p = __expf(z[r]) * mc;
            int ql = (r & 3) + 8 * (r >> 2) + 4 * half;
            Pw[ql * 40 + l31] = f2bf_n(p);
        }
        // wave-private: in-wave lgkmcnt ordering, no barrier
        bf16x8 pf[2];
#pragma unroll
        for (int sp = 0; sp < 2; ++sp)
            pf[sp] = ld8(&Pw[l31 * 40 + sp * 16 + half * 8]);
        // PV + ones over this wave's key chunk
#pragma unroll
        for (int d = 0; d < 2; ++d) {
            int rV = d * 32 + l31;
#pragma unroll
            for (int sp = 0; sp < 2; ++sp) {
                int chunk = ksub * 4 + sp * 2 + half;
                bf16x8 vf = ld8(&Vs[rV * 128 + ((chunk ^ (rV & 15)) << 3)]);
                accd[d] = __builtin_amdgcn_mfma_f32_32x32x16_bf16(
                    pf[sp], vf, accd[d], 0, 0, 0);
            }
        }
#pragma unroll
        for (int sp = 0; sp < 2; ++sp)
            accl = __builtin_amdgcn_mfma_f32_32x32x16_bf16(
                pf[sp], ones_f, accl, 0, 0, 0);
    }

    // ---- 4-way split-K merge, staged (peak overlay 4 strips = 49,152 B) ----
    __syncthreads();
    if (ksub >= 2) {                     // round A writers: ksub 2,3
        float* q_ = mrg + (qg * 2 + (ksub - 2)) * 3072;   // [48][64] f32
#pragma unroll
        for (int r = 0; r < 16; ++r) {
            q_[(r) * 64 + lane]      = accd[0][r];
            q_[(16 + r) * 64 + lane] = accd[1][r];
            q_[(32 + r) * 64 + lane] = accl[r];
        }
    }
    __syncthreads();
    if (ksub < 2) {                      // round A adders: ksub 0,1
        const float* q_ = mrg + (qg * 2 + ksub) * 3072;
#pragma unroll
        for (int r = 0; r < 16; ++r) {
            accd[0][r] += q_[(r) * 64 + lane];
            accd[1][r] += q_[(16 + r) * 64 + lane];
            accl[r]    += q_[(32 + r) * 64 + lane];
        }
    }
    __syncthreads();
    if (ksub == 1) {                     // round B writer
        float* q_ = mrg + qg * 3072;
#pragma unroll
        for (int r = 0; r < 16; ++r) {
            q_[(r) * 64 + lane]      = accd[0][r];
            q_[(16 + r) * 64 + lane] = accd[1][r];
            q_[(32 + r) * 64 + lane] = accl[r];
        }
    }
    __syncthreads();
    if (ksub == 0) {                     // round B adder + epilogue
        const float* q_ = mrg + qg * 3072;
#pragma unroll
        for (int r = 0; r < 16; ++r) {
            accd[0][r] += q_[(r) * 64 + lane];
            accd[1][r] += q_[(16 + r) * 64 + lane];
            accl[r]    += q_[(32 + r) * 64 + lane];
        }
#pragma unroll
        for (int r = 0; r < 16; ++r) {
            int ql = (r & 3) + 8 * (r >> 2) + 4 * half;
            int q = q0 + qg * 32 + ql;
            float mq = mask[b * 2048 + q];
            float lr = __shfl(accl[r], half * 32, 64);
            float inv = mq / (lr + 1e-13f);
#pragma unroll
            for (int d = 0; d < 2; ++d)
                Xattn[(b * 2048 + q) * 1024 + (bh & 15) * 64 + d * 32 + l31] =
                    f2bf_n(accd[d][r] * inv);
        }
    }
}

// ---------------------------------------------------------------------------
// Output projection — round-8 structure (BK=64 single-buffer), 64x128 tiles,
// grid (64, 8) = 512 blocks. f32 out.
// ---------------------------------------------------------------------------
__global__ __launch_bounds__(256) void oproj_kernel(
    const unsigned short* __restrict__ A, const unsigned short* __restrict__ W,
    const float* __restrict__ bias, float* __restrict__ out)
{
    __shared__ __align__(16) unsigned short As[64 * 64];
    __shared__ __align__(16) unsigned short Bs[128 * 64];

    const int t = threadIdx.x;
    const int lane = t & 63, w = t >> 6;
    const int l15 = lane & 15, grp = lane >> 4;
    const int m0 = blockIdx.x * 64;
    const int e0 = blockIdx.y * 128;
    const int srow = lane >> 3, sc_ = lane & 7;

    f32x4 acc[4][2];
#pragma unroll
    for (int i = 0; i < 4; ++i)
#pragma unroll
        for (int j = 0; j < 2; ++j) acc[i][j] = (f32x4){0.f, 0.f, 0.f, 0.f};

    for (int kt = 0; kt < 16; ++kt) {
        const int k0 = kt * 64;
        __syncthreads();
#pragma unroll
        for (int jj = 0; jj < 2; ++jj) {
            int chunk = w * 2 + jj;
            int row = chunk * 8 + srow;
            int cs = sc_ ^ (row & 7);
            ldsdma16(&As[chunk * 512], &A[(m0 + row) * 1024 + k0 + cs * 8]);
        }
#pragma unroll
        for (int jj = 0; jj < 4; ++jj) {
            int chunk = w * 4 + jj;
            int row = chunk * 8 + srow;
            int cs = sc_ ^ (row & 7);
            ldsdma16(&Bs[chunk * 512], &W[(e0 + row) * 1024 + k0 + cs * 8]);
        }
        __syncthreads();
#pragma unroll
        for (int kk = 0; kk < 64; kk += 32) {
            const int cb = kk >> 3;
            bf16x8 af[4], bfr[2];
#pragma unroll
            for (int i = 0; i < 4; ++i) {
                int r = i * 16 + l15;
                af[i] = ld8(&As[r * 64 + (((cb + grp) ^ (r & 7)) << 3)]);
            }
#pragma unroll
            for (int j = 0; j < 2; ++j) {
                int r = w * 32 + j * 16 + l15;
                bfr[j] = ld8(&Bs[r * 64 + (((cb + grp) ^ (r & 7)) << 3)]);
            }
#pragma unroll
            for (int i = 0; i < 4; ++i)
#pragma unroll
                for (int j = 0; j < 2; ++j)
                    acc[i][j] = __builtin_amdgcn_mfma_f32_16x16x32_bf16(
                        af[i], bfr[j], acc[i][j], 0, 0, 0);
        }
    }

#pragma unroll
    for (int j = 0; j < 2; ++j) {
        int e = e0 + w * 32 + j * 16 + l15;
        float bv_ = bias[e];
#pragma unroll
        for (int i = 0; i < 4; ++i)
#pragma unroll
            for (int r = 0; r < 4; ++r) {
                int token = m0 + i * 16 + grp * 4 + r;
                out[token * 1024 + e] = acc[i][j][r] + bv_;
            }
    }
}

extern "C" void kernel_launch(void* const* d_in, const int* in_sizes, int n_in,
                              void* d_out, int out_size, void* d_ws, size_t ws_size,
                              hipStream_t stream) {
    const float* x    = (const float*)d_in[0];
    const float* mask = (const float*)d_in[1];
    const float* Wq   = (const float*)d_in[2];
    const float* bq   = (const float*)d_in[3];
    const float* Wk   = (const float*)d_in[4];
    const float* bk   = (const float*)d_in[5];
    const float* Wv   = (const float*)d_in[6];
    const float* bv   = (const float*)d_in[7];
    const float* Wo   = (const float*)d_in[8];
    const float* bo   = (const float*)d_in[9];
    float* out = (float*)d_out;

    unsigned short* Qws   = (unsigned short*)d_ws;   // u16 element offsets:
    unsigned short* Kws   = Qws + 4194304;
    unsigned short* VT    = Qws + 8388608;
    unsigned short* Xattn = Qws + 12582912;
    unsigned short* Xb    = Qws + 16777216;
    unsigned short* Wb    = Qws + 20971520;          // [Wq|Wk|Wv|Wo], end = 48 MB

    conv_kernel<<<dim3(8192), 256, 0, stream>>>(x, Wq, Wk, Wv, Wo, Xb, Wb);
    qkv_kernel<<<dim3(32, 24), 256, 0, stream>>>(Xb, Wb, bq, bk, bv, Qws, Kws, VT);
    attn_kernel<<<dim3(32, 32), 512, 0, stream>>>(Qws, Kws, VT, mask, Xattn);
    oproj_kernel<<<dim3(64, 8), 256, 0, stream>>>(Xattn, Wb + 3145728, bo, out);
}

// Round 14
// 193.606 us; speedup vs baseline: 1.6632x; 1.6632x over previous
//
#include <hip/hip_runtime.h>
#include <stdint.h>

#define DEV __device__ __forceinline__

typedef __attribute__((ext_vector_type(4))) float f32x4;
typedef __attribute__((ext_vector_type(16))) float f32x16;
typedef __attribute__((ext_vector_type(8))) __bf16 bf16x8;
typedef __attribute__((ext_vector_type(4))) __bf16 bf16x4;
typedef __attribute__((ext_vector_type(8))) short short8;
typedef __attribute__((ext_vector_type(4))) unsigned short u16x4;

DEV unsigned short f2bf_n(float f) {             // native cvt (RNE, 1 op)
    __bf16 h = (__bf16)f;
    return __builtin_bit_cast(unsigned short, h);
}
DEV bf16x8 ld8(const unsigned short* p) {        // 16B vector load (LDS or global)
    short8 v = *(const short8*)p;
    return __builtin_bit_cast(bf16x8, v);
}
// async global->LDS DMA, 16B per lane. lds base wave-uniform; HW adds lane*16.
DEV void ldsdma16(unsigned short* lds, const unsigned short* g) {
    __builtin_amdgcn_global_load_lds(
        (const __attribute__((address_space(1))) unsigned int*)g,
        (__attribute__((address_space(3))) unsigned int*)lds, 16, 0, 0);
}

// ---------------------------------------------------------------------------
// Pre-convert f32 -> bf16: X (4.19M el) then Wq|Wk|Wv|Wo (1.05M each).
// ---------------------------------------------------------------------------
__global__ __launch_bounds__(256) void conv_kernel(
    const float* __restrict__ X,
    const float* __restrict__ Wq, const float* __restrict__ Wk,
    const float* __restrict__ Wv, const float* __restrict__ Wo,
    unsigned short* __restrict__ Xb, unsigned short* __restrict__ Wb)
{
    int c = blockIdx.x * 256 + threadIdx.x;      // chunk of 4 floats
    const float* src;
    unsigned short* dst;
    if (c < 1048576) {
        src = X + c * 4; dst = Xb + c * 4;
    } else {
        int c2 = c - 1048576;
        int wsel = c2 >> 18;
        int off = (c2 & 262143) * 4;
        const float* ws_[4] = { Wq, Wk, Wv, Wo };
        src = ws_[wsel] + off;
        dst = Wb + wsel * 1048576 + off;
    }
    f32x4 v = *(const f32x4*)src;
    bf16x4 b = { (__bf16)v[0], (__bf16)v[1], (__bf16)v[2], (__bf16)v[3] };
    *(bf16x4*)dst = b;
}

// ---------------------------------------------------------------------------
// Fused QKV projection — 128x128 tile, BK=64 single-buffer DMA staging,
// now EIGHT waves (512 thr): staging shared by 2x the waves (round-7 pattern),
// per-wave DMA instrs 8 -> 4, waves/CU 12 -> 24. Math order identical.
// grid (32, 24): y: 0-7 Q, 8-15 K, 16-23 V. Epilogues repack via LDS.
// ---------------------------------------------------------------------------
__global__ __launch_bounds__(512) void qkv_kernel(
    const unsigned short* __restrict__ Xb, const unsigned short* __restrict__ Wb,
    const float* __restrict__ bq, const float* __restrict__ bk,
    const float* __restrict__ bv,
    unsigned short* __restrict__ Qws, unsigned short* __restrict__ Kws,
    unsigned short* __restrict__ VT)
{
    // union: staging As|Bs (2 x 8192 el) vs repack tile (128 x 136 el)
    __shared__ __align__(16) unsigned short SMEM[17408];
    unsigned short* As = SMEM;
    unsigned short* Bs = SMEM + 8192;

    const int t = threadIdx.x;
    const int lane = t & 63, w = t >> 6;         // 8 waves
    const int wm = w & 1, wn = w >> 1;           // wave owns 64m x 32n
    const int l15 = lane & 15, grp = lane >> 4;
    const int m0 = blockIdx.x * 128;
    const int which = blockIdx.y >> 3;
    const int e0 = (blockIdx.y & 7) * 128;

    const unsigned short* Wmat = Wb + which * 1048576;
    const float* bias = (which == 0) ? bq : (which == 1) ? bk : bv;

    f32x4 acc[4][2];
#pragma unroll
    for (int i = 0; i < 4; ++i)
#pragma unroll
        for (int j = 0; j < 2; ++j) acc[i][j] = (f32x4){0.f, 0.f, 0.f, 0.f};

    for (int kt = 0; kt < 16; ++kt) {
        const int k0 = kt * 64;
        __syncthreads();
#pragma unroll
        for (int ii = 0; ii < 2; ++ii) {         // 16 A + 16 B instrs, 2+2/wave
            int inst = w * 2 + ii;
            int row = inst * 8 + (lane >> 3);    // 0..127
            int cs = (lane & 7) ^ (row & 7);     // global-side swizzle
            ldsdma16(&As[inst * 512], &Xb[(m0 + row) * 1024 + k0 + cs * 8]);
            ldsdma16(&Bs[inst * 512], &Wmat[(e0 + row) * 1024 + k0 + cs * 8]);
        }
        __syncthreads();
#pragma unroll
        for (int kk = 0; kk < 64; kk += 32) {
            const int cb = kk >> 3;
            bf16x8 af[4], bfr[2];
#pragma unroll
            for (int i = 0; i < 4; ++i) {
                int r = wm * 64 + i * 16 + l15;
                af[i] = ld8(&As[r * 64 + (((cb + grp) ^ (r & 7)) << 3)]);
            }
#pragma unroll
            for (int j = 0; j < 2; ++j) {
                int r = wn * 32 + j * 16 + l15;
                bfr[j] = ld8(&Bs[r * 64 + (((cb + grp) ^ (r & 7)) << 3)]);
            }
#pragma unroll
            for (int i = 0; i < 4; ++i)
#pragma unroll
                for (int j = 0; j < 2; ++j)
                    acc[i][j] = __builtin_amdgcn_mfma_f32_16x16x32_bf16(
                        af[i], bfr[j], acc[i][j], 0, 0, 0);
        }
    }

    __syncthreads();                     // all waves done reading As/Bs
    const int b = m0 >> 11;

    if (which == 2) {
        // ---- V: repack [e][token], then coalesced V^T stores ----
#pragma unroll
        for (int j = 0; j < 2; ++j) {
            int e = e0 + wn * 32 + j * 16 + l15;
            float bv_ = bias[e];
#pragma unroll
            for (int i = 0; i < 4; ++i) {
                u16x4 pk;
#pragma unroll
                for (int r = 0; r < 4; ++r) pk[r] = f2bf_n(acc[i][j][r] + bv_);
                *(u16x4*)&SMEM[(wn * 32 + j * 16 + l15) * 136 +
                               wm * 64 + i * 16 + grp * 4] = pk;
            }
        }
        __syncthreads();
        const int s0 = m0 & 2047;
#pragma unroll
        for (int round = 0; round < 4; ++round) {
            int dhl = (t >> 4) + round * 32;     // 0..127 over e-tile
            int chunk = t & 15;                  // 16 x 8el = 128 tokens
            int h = (e0 + dhl) >> 6, dh = (e0 + dhl) & 63;
            *(short8*)&VT[((b * 16 + h) * 64 + dh) * 2048 + s0 + chunk * 8] =
                *(const short8*)&SMEM[dhl * 136 + chunk * 8];
        }
    } else {
        // ---- Q / K: repack [token][e], then coalesced 16B stores ----
        const float scale = (which == 0) ? 0.125f : 1.0f;
#pragma unroll
        for (int j = 0; j < 2; ++j) {
            int e = e0 + wn * 32 + j * 16 + l15;
            float bv_ = bias[e];
#pragma unroll
            for (int i = 0; i < 4; ++i)
#pragma unroll
                for (int r = 0; r < 4; ++r)
                    SMEM[(wm * 64 + i * 16 + grp * 4 + r) * 136 +
                         wn * 32 + j * 16 + l15] =
                        f2bf_n((acc[i][j][r] + bv_) * scale);
        }
        __syncthreads();
        unsigned short* dst = (which == 0) ? Qws : Kws;
#pragma unroll
        for (int round = 0; round < 4; ++round) {
            int tl = (t >> 4) + round * 32;      // 0..127 token row
            int chunk = t & 15;                  // 16 x 8el = 128 e cols
            int e = e0 + chunk * 8;
            int h = e >> 6, dh = e & 63;
            int s = (m0 & 2047) + tl;
            *(short8*)&dst[((b * 16 + h) * 2048 + s) * 64 + dh] =
                *(const short8*)&SMEM[tl * 136 + chunk * 8];
        }
    }
}

// ---------------------------------------------------------------------------
// Flash attention v5 (round-12 verbatim — best measured, 59 us):
// 32x32x16 + 2-way split-K + half-width Ps (stride 40). LDS 53,248 B.
// grid (16, 32), 512 thr, wave = (khalf=w>>2, qg=w&3). K/V re-read
// multiplicity per head stays 16 blocks (round-13 showed 32 collapses L2/L3).
// ---------------------------------------------------------------------------
__global__ __launch_bounds__(512, 4) void attn_kernel(
    const unsigned short* __restrict__ Qws, const unsigned short* __restrict__ Kws,
    const unsigned short* __restrict__ VT, const float* __restrict__ mask,
    unsigned short* __restrict__ Xattn)
{
    // Ks 128x64 (8192 el) | Vs 64x128 (8192 el) | Ps 8 x 32 x 40 (10240 el)
    __shared__ __align__(16) unsigned short SMEM[26624];   // 53,248 B
    unsigned short* Ks = SMEM;                    // [key][dh],  8-chunk swizzle
    unsigned short* Vs = SMEM + 8192;             // [dh][key], 16-chunk swizzle
    unsigned short* Ps = SMEM + 16384;            // per-wave 32x40 strips
    float* mrg = (float*)SMEM;                    // merge overlay (48 KB fits)

    const int t = threadIdx.x;
    const int lane = t & 63, w = t >> 6;          // 8 waves
    const int l31 = lane & 31, half = lane >> 5;
    const int qg = w & 3, khalf = w >> 2;
    const int q0 = blockIdx.x * 128;
    const int bh = blockIdx.y;
    const int b = bh >> 4;

    const unsigned short* Kp = Kws + (size_t)bh * 131072;  // [key][dh]
    const unsigned short* Vp = VT  + (size_t)bh * 131072;  // [dh][key]

    // Q A-frags (persistent)
    bf16x8 qf[4];
#pragma unroll
    for (int s = 0; s < 4; ++s)
        qf[s] = ld8(&Qws[(bh * 2048 + q0 + qg * 32 + l31) * 64 + s * 16 + half * 8]);

    // ones B-frag: B[n][k]=1 iff n==0
    short onev = (l31 == 0) ? (short)0x3F80 : (short)0;
    short8 ov = { onev, onev, onev, onev, onev, onev, onev, onev };
    bf16x8 ones_f = __builtin_bit_cast(bf16x8, ov);

    unsigned short* Pw = Ps + w * 1280;           // this wave's 32x40 strip

    f32x16 accd[2], accl;
#pragma unroll
    for (int d = 0; d < 2; ++d)
#pragma unroll
        for (int r = 0; r < 16; ++r) accd[d][r] = 0.f;
#pragma unroll
    for (int r = 0; r < 16; ++r) accl[r] = 0.f;

    for (int kb = 0; kb < 16; ++kb) {
        const int k0 = kb * 128;
        __syncthreads();                 // prev tile's readers done
#pragma unroll
        for (int ii = 0; ii < 2; ++ii) { // Ks: 16 DMA (8 rows x 128B), 2/wave
            int inst = w * 2 + ii;
            int row = inst * 8 + (lane >> 3);
            int cs = (lane & 7) ^ (row & 7);
            ldsdma16(&Ks[inst * 512], &Kp[(k0 + row) * 64 + cs * 8]);
        }
#pragma unroll
        for (int ii = 0; ii < 2; ++ii) { // Vs: 16 DMA (4 rows x 256B), 2/wave
            int inst = w * 2 + ii;
            int row = inst * 4 + (lane >> 4);
            int cs = (lane & 15) ^ (row & 15);
            ldsdma16(&Vs[inst * 512], &Vp[row * 2048 + k0 + cs * 8]);
        }
        float mc[2];
#pragma unroll
        for (int g = 0; g < 2; ++g)
            mc[g] = mask[b * 2048 + k0 + khalf * 64 + g * 32 + l31];
        __syncthreads();                 // DMA drained

#pragma unroll
        for (int g = 0; g < 2; ++g) {
            // S = Q.K^T over this g's 32 keys
            f32x16 z;
#pragma unroll
            for (int r = 0; r < 16; ++r) z[r] = 0.f;
            int rK = khalf * 64 + g * 32 + l31;
#pragma unroll
            for (int s = 0; s < 4; ++s) {
                int chunk = s * 2 + half;
                bf16x8 kf = ld8(&Ks[rK * 64 + ((chunk ^ (rK & 7)) << 3)]);
                z = __builtin_amdgcn_mfma_f32_32x32x16_bf16(qf[s], kf, z, 0, 0, 0);
            }
            // P = exp(s)*m into wave-private half-width strip (col = l31)
#pragma unroll
            for (int r = 0; r < 16; ++r) {
                float p = __expf(z[r]) * mc[g];
                int ql = (r & 3) + 8 * (r >> 2) + 4 * half;
                Pw[ql * 40 + l31] = f2bf_n(p);
            }
            // wave-private: in-wave lgkmcnt ordering, no barrier
            bf16x8 pf[2];
#pragma unroll
            for (int sp = 0; sp < 2; ++sp)
                pf[sp] = ld8(&Pw[l31 * 40 + sp * 16 + half * 8]);
            // PV + ones; chunk order matches v4 exactly (bit-exact accumulate)
#pragma unroll
            for (int d = 0; d < 2; ++d) {
                int rV = d * 32 + l31;
#pragma unroll
                for (int sp = 0; sp < 2; ++sp) {
                    int chunk = khalf * 8 + g * 4 + sp * 2 + half;
                    bf16x8 vf = ld8(&Vs[rV * 128 + ((chunk ^ (rV & 15)) << 3)]);
                    accd[d] = __builtin_amdgcn_mfma_f32_32x32x16_bf16(
                        pf[sp], vf, accd[d], 0, 0, 0);
                }
            }
#pragma unroll
            for (int sp = 0; sp < 2; ++sp)
                accl = __builtin_amdgcn_mfma_f32_32x32x16_bf16(
                    pf[sp], ones_f, accl, 0, 0, 0);
        }
    }

    // ---- split-K merge: khalf=1 writes partials, khalf=0 adds ----
    __syncthreads();
    if (khalf == 1) {
        float* q_ = mrg + qg * 3072;     // [48][64] f32
#pragma unroll
        for (int r = 0; r < 16; ++r) {
            q_[(r) * 64 + lane]      = accd[0][r];
            q_[(16 + r) * 64 + lane] = accd[1][r];
            q_[(32 + r) * 64 + lane] = accl[r];
        }
    }
    __syncthreads();
    if (khalf == 0) {
        const float* q_ = mrg + qg * 3072;
#pragma unroll
        for (int r = 0; r < 16; ++r) {
            accd[0][r] += q_[(r) * 64 + lane];
            accd[1][r] += q_[(16 + r) * 64 + lane];
            accl[r]    += q_[(32 + r) * 64 + lane];
        }
#pragma unroll
        for (int r = 0; r < 16; ++r) {
            int ql = (r & 3) + 8 * (r >> 2) + 4 * half;
            int q = q0 + qg * 32 + ql;
            float mq = mask[b * 2048 + q];
            float lr = __shfl(accl[r], half * 32, 64);
            float inv = mq / (lr + 1e-13f);
#pragma unroll
            for (int d = 0; d < 2; ++d)
                Xattn[(b * 2048 + q) * 1024 + (bh & 15) * 64 + d * 32 + l31] =
                    f2bf_n(accd[d][r] * inv);
        }
    }
}

// ---------------------------------------------------------------------------
// Output projection — round-8 structure (BK=64 single-buffer), 64x128 tiles,
// grid (64, 8) = 512 blocks. f32 out.
// ---------------------------------------------------------------------------
__global__ __launch_bounds__(256) void oproj_kernel(
    const unsigned short* __restrict__ A, const unsigned short* __restrict__ W,
    const float* __restrict__ bias, float* __restrict__ out)
{
    __shared__ __align__(16) unsigned short As[64 * 64];
    __shared__ __align__(16) unsigned short Bs[128 * 64];

    const int t = threadIdx.x;
    const int lane = t & 63, w = t >> 6;
    const int l15 = lane & 15, grp = lane >> 4;
    const int m0 = blockIdx.x * 64;
    const int e0 = blockIdx.y * 128;
    const int srow = lane >> 3, sc_ = lane & 7;

    f32x4 acc[4][2];
#pragma unroll
    for (int i = 0; i < 4; ++i)
#pragma unroll
        for (int j = 0; j < 2; ++j) acc[i][j] = (f32x4){0.f, 0.f, 0.f, 0.f};

    for (int kt = 0; kt < 16; ++kt) {
        const int k0 = kt * 64;
        __syncthreads();
#pragma unroll
        for (int jj = 0; jj < 2; ++jj) {
            int chunk = w * 2 + jj;
            int row = chunk * 8 + srow;
            int cs = sc_ ^ (row & 7);
            ldsdma16(&As[chunk * 512], &A[(m0 + row) * 1024 + k0 + cs * 8]);
        }
#pragma unroll
        for (int jj = 0; jj < 4; ++jj) {
            int chunk = w * 4 + jj;
            int row = chunk * 8 + srow;
            int cs = sc_ ^ (row & 7);
            ldsdma16(&Bs[chunk * 512], &W[(e0 + row) * 1024 + k0 + cs * 8]);
        }
        __syncthreads();
#pragma unroll
        for (int kk = 0; kk < 64; kk += 32) {
            const int cb = kk >> 3;
            bf16x8 af[4], bfr[2];
#pragma unroll
            for (int i = 0; i < 4; ++i) {
                int r = i * 16 + l15;
                af[i] = ld8(&As[r * 64 + (((cb + grp) ^ (r & 7)) << 3)]);
            }
#pragma unroll
            for (int j = 0; j < 2; ++j) {
                int r = w * 32 + j * 16 + l15;
                bfr[j] = ld8(&Bs[r * 64 + (((cb + grp) ^ (r & 7)) << 3)]);
            }
#pragma unroll
            for (int i = 0; i < 4; ++i)
#pragma unroll
                for (int j = 0; j < 2; ++j)
                    acc[i][j] = __builtin_amdgcn_mfma_f32_16x16x32_bf16(
                        af[i], bfr[j], acc[i][j], 0, 0, 0);
        }
    }

#pragma unroll
    for (int j = 0; j < 2; ++j) {
        int e = e0 + w * 32 + j * 16 + l15;
        float bv_ = bias[e];
#pragma unroll
        for (int i = 0; i < 4; ++i)
#pragma unroll
            for (int r = 0; r < 4; ++r) {
                int token = m0 + i * 16 + grp * 4 + r;
                out[token * 1024 + e] = acc[i][j][r] + bv_;
            }
    }
}

extern "C" void kernel_launch(void* const* d_in, const int* in_sizes, int n_in,
                              void* d_out, int out_size, void* d_ws, size_t ws_size,
                              hipStream_t stream) {
    const float* x    = (const float*)d_in[0];
    const float* mask = (const float*)d_in[1];
    const float* Wq   = (const float*)d_in[2];
    const float* bq   = (const float*)d_in[3];
    const float* Wk   = (const float*)d_in[4];
    const float* bk   = (const float*)d_in[5];
    const float* Wv   = (const float*)d_in[6];
    const float* bv   = (const float*)d_in[7];
    const float* Wo   = (const float*)d_in[8];
    const float* bo   = (const float*)d_in[9];
    float* out = (float*)d_out;

    unsigned short* Qws   = (unsigned short*)d_ws;   // u16 element offsets:
    unsigned short* Kws   = Qws + 4194304;
    unsigned short* VT    = Qws + 8388608;
    unsigned short* Xattn = Qws + 12582912;
    unsigned short* Xb    = Qws + 16777216;
    unsigned short* Wb    = Qws + 20971520;          // [Wq|Wk|Wv|Wo], end = 48 MB

    conv_kernel<<<dim3(8192), 256, 0, stream>>>(x, Wq, Wk, Wv, Wo, Xb, Wb);
    qkv_kernel<<<dim3(32, 24), 512, 0, stream>>>(Xb, Wb, bq, bk, bv, Qws, Kws, VT);
    attn_kernel<<<dim3(16, 32), 512, 0, stream>>>(Qws, Kws, VT, mask, Xattn);
    oproj_kernel<<<dim3(64, 8), 256, 0, stream>>>(Xattn, Wb + 3145728, bo, out);
}

// Round 15
// 183.870 us; speedup vs baseline: 1.7513x; 1.0530x over previous
//
#include <hip/hip_runtime.h>
#include <stdint.h>

#define DEV __device__ __forceinline__

typedef __attribute__((ext_vector_type(4))) float f32x4;
typedef __attribute__((ext_vector_type(16))) float f32x16;
typedef __attribute__((ext_vector_type(8))) __bf16 bf16x8;
typedef __attribute__((ext_vector_type(4))) __bf16 bf16x4;
typedef __attribute__((ext_vector_type(8))) short short8;
typedef __attribute__((ext_vector_type(4))) unsigned short u16x4;

DEV unsigned short f2bf_n(float f) {
    __bf16 h = (__bf16)f;
    return __builtin_bit_cast(unsigned short, h);
}
DEV bf16x8 ld8(const unsigned short* p) {
    short8 v = *(const short8*)p;
    return __builtin_bit_cast(bf16x8, v);
}
DEV void ldsdma16(unsigned short* lds, const unsigned short* g) {
    __builtin_amdgcn_global_load_lds(
        (const __attribute__((address_space(1))) unsigned int*)g,
        (__attribute__((address_space(3))) unsigned int*)lds, 16, 0, 0);
}

// ---------------------------------------------------------------------------
// Token compaction: per batch b, sidx[b][j] = s of j-th unmasked token,
// hdr[b] = nb, hdr[2+b] = nbp (nb padded up to multiple of 128).
// ---------------------------------------------------------------------------
__global__ __launch_bounds__(256) void compact_kernel(
    const float* __restrict__ mask, int* __restrict__ sidx, int* __restrict__ hdr)
{
    __shared__ int part[256];
    __shared__ int nb_sh;
    const int b = blockIdx.x, t = threadIdx.x;
    int loc[8], cnt = 0;
#pragma unroll
    for (int k = 0; k < 8; ++k) {
        loc[k] = (mask[b * 2048 + t * 8 + k] > 0.5f) ? 1 : 0;
        cnt += loc[k];
    }
    part[t] = cnt;
    __syncthreads();
    if (t == 0) {
        int run = 0;
        for (int i = 0; i < 256; ++i) { int v = part[i]; part[i] = run; run += v; }
        nb_sh = run;
        hdr[b] = run;
        hdr[2 + b] = (run + 127) & ~127;
    }
    __syncthreads();
    int base = part[t];
#pragma unroll
    for (int k = 0; k < 8; ++k)
        if (loc[k]) sidx[b * 2048 + (base++)] = t * 8 + k;
    for (int j = nb_sh + t; j < 2048; j += 256) sidx[b * 2048 + j] = -1;
}

// ---------------------------------------------------------------------------
// W f32 -> bf16 (Wq|Wk|Wv|Wo), 4096 blocks x 256 thr x 4 el.
// ---------------------------------------------------------------------------
__global__ __launch_bounds__(256) void wconv_kernel(
    const float* __restrict__ Wq, const float* __restrict__ Wk,
    const float* __restrict__ Wv, const float* __restrict__ Wo,
    unsigned short* __restrict__ Wb)
{
    int c = blockIdx.x * 256 + threadIdx.x;
    int wsel = c >> 18, off = (c & 262143) * 4;
    const float* ws_[4] = { Wq, Wk, Wv, Wo };
    f32x4 v = *(const f32x4*)(ws_[wsel] + off);
    bf16x4 b = { (__bf16)v[0], (__bf16)v[1], (__bf16)v[2], (__bf16)v[3] };
    *(bf16x4*)&Wb[wsel * 1048576 + off] = b;
}

// ---------------------------------------------------------------------------
// Gather + convert X into compact bf16 rows; zero-fill pad rows [nb, nbp).
// grid 4096: rb = b*2048 + j.
// ---------------------------------------------------------------------------
__global__ __launch_bounds__(256) void gatherx_kernel(
    const float* __restrict__ X, const int* __restrict__ sidx,
    const int* __restrict__ hdr, unsigned short* __restrict__ Xc)
{
    const int rb = blockIdx.x;
    const int b = rb >> 11, j = rb & 2047;
    if (j >= hdr[2 + b]) return;
    const int col = threadIdx.x * 4;
    bf16x4 o;
    if (j < hdr[b]) {
        int s = sidx[b * 2048 + j];
        f32x4 v = *(const f32x4*)&X[(size_t)(b * 2048 + s) * 1024 + col];
        o = (bf16x4){ (__bf16)v[0], (__bf16)v[1], (__bf16)v[2], (__bf16)v[3] };
    } else {
        o = (bf16x4){ (__bf16)0.f, (__bf16)0.f, (__bf16)0.f, (__bf16)0.f };
    }
    *(bf16x4*)&Xc[(size_t)rb * 1024 + col] = o;
}

// ---------------------------------------------------------------------------
// out init: every token's output = bo (exact answer for masked tokens;
// unmasked rows overwritten by oproj scatter).
// ---------------------------------------------------------------------------
__global__ __launch_bounds__(256) void oinit_kernel(
    const float* __restrict__ bo, float* __restrict__ out)
{
    int e = threadIdx.x * 4;
    f32x4 v = *(const f32x4*)&bo[e];
    *(f32x4*)&out[(size_t)blockIdx.x * 1024 + e] = v;
}

// ---------------------------------------------------------------------------
// Fused QKV projection on COMPACT rows (round-12 structure: 256 thr, BK=64
// single-buffer DMA staging). Blocks beyond nbp(b) exit. grid (32, 24).
// ---------------------------------------------------------------------------
__global__ __launch_bounds__(256) void qkv_kernel(
    const unsigned short* __restrict__ Xc, const unsigned short* __restrict__ Wb,
    const float* __restrict__ bq, const float* __restrict__ bk,
    const float* __restrict__ bv, const int* __restrict__ hdr,
    unsigned short* __restrict__ Qc, unsigned short* __restrict__ Kc,
    unsigned short* __restrict__ VTc)
{
    __shared__ __align__(16) unsigned short SMEM[17408];
    unsigned short* As = SMEM;
    unsigned short* Bs = SMEM + 8192;

    const int m0 = blockIdx.x * 128;
    const int b = m0 >> 11;
    if ((m0 & 2047) >= hdr[2 + b]) return;

    const int t = threadIdx.x;
    const int lane = t & 63, w = t >> 6;
    const int wm = w & 1, wn = w >> 1;
    const int l15 = lane & 15, grp = lane >> 4;
    const int which = blockIdx.y >> 3;
    const int e0 = (blockIdx.y & 7) * 128;

    const unsigned short* Wmat = Wb + which * 1048576;
    const float* bias = (which == 0) ? bq : (which == 1) ? bk : bv;

    const int srow = lane >> 3, sc_ = lane & 7;

    f32x4 acc[4][4];
#pragma unroll
    for (int i = 0; i < 4; ++i)
#pragma unroll
        for (int j = 0; j < 4; ++j) acc[i][j] = (f32x4){0.f, 0.f, 0.f, 0.f};

    for (int kt = 0; kt < 16; ++kt) {
        const int k0 = kt * 64;
        __syncthreads();
#pragma unroll
        for (int j = 0; j < 4; ++j) {
            int row = (w * 4 + j) * 8 + srow;
            int cs = sc_ ^ (row & 7);
            ldsdma16(&As[(w * 4 + j) * 512],
                     &Xc[(m0 + row) * 1024 + k0 + cs * 8]);
            ldsdma16(&Bs[(w * 4 + j) * 512],
                     &Wmat[(e0 + row) * 1024 + k0 + cs * 8]);
        }
        __syncthreads();
#pragma unroll
        for (int kk = 0; kk < 64; kk += 32) {
            const int cb = kk >> 3;
            bf16x8 af[4], bfr[4];
#pragma unroll
            for (int i = 0; i < 4; ++i) {
                int r = wm * 64 + i * 16 + l15;
                af[i] = ld8(&As[r * 64 + (((cb + grp) ^ (r & 7)) << 3)]);
            }
#pragma unroll
            for (int j = 0; j < 4; ++j) {
                int r = wn * 64 + j * 16 + l15;
                bfr[j] = ld8(&Bs[r * 64 + (((cb + grp) ^ (r & 7)) << 3)]);
            }
#pragma unroll
            for (int i = 0; i < 4; ++i)
#pragma unroll
                for (int j = 0; j < 4; ++j)
                    acc[i][j] = __builtin_amdgcn_mfma_f32_16x16x32_bf16(
                        af[i], bfr[j], acc[i][j], 0, 0, 0);
        }
    }

    __syncthreads();

    if (which == 2) {
        // V: repack [e][token], coalesced V^T stores (compact j coords)
#pragma unroll
        for (int j = 0; j < 4; ++j) {
            int e = e0 + wn * 64 + j * 16 + l15;
            float bv_ = bias[e];
#pragma unroll
            for (int i = 0; i < 4; ++i) {
                u16x4 pk;
#pragma unroll
                for (int r = 0; r < 4; ++r) pk[r] = f2bf_n(acc[i][j][r] + bv_);
                *(u16x4*)&SMEM[(wn * 64 + j * 16 + l15) * 136 +
                               wm * 64 + i * 16 + grp * 4] = pk;
            }
        }
        __syncthreads();
        const int s0 = m0 & 2047;
#pragma unroll
        for (int round = 0; round < 8; ++round) {
            int dhl = (t >> 4) + round * 16;
            int chunk = t & 15;
            int h = (e0 + dhl) >> 6, dh = (e0 + dhl) & 63;
            *(short8*)&VTc[((b * 16 + h) * 64 + dh) * 2048 + s0 + chunk * 8] =
                *(const short8*)&SMEM[dhl * 136 + chunk * 8];
        }
    } else {
        // Q / K: repack [token][e], coalesced 16B stores (compact j coords)
        const float scale = (which == 0) ? 0.125f : 1.0f;
#pragma unroll
        for (int j = 0; j < 4; ++j) {
            int e = e0 + wn * 64 + j * 16 + l15;
            float bv_ = bias[e];
#pragma unroll
            for (int i = 0; i < 4; ++i)
#pragma unroll
                for (int r = 0; r < 4; ++r)
                    SMEM[(wm * 64 + i * 16 + grp * 4 + r) * 136 +
                         wn * 64 + j * 16 + l15] =
                        f2bf_n((acc[i][j][r] + bv_) * scale);
        }
        __syncthreads();
        unsigned short* dst = (which == 0) ? Qc : Kc;
#pragma unroll
        for (int round = 0; round < 8; ++round) {
            int tl = (t >> 4) + round * 16;
            int chunk = t & 15;
            int e = e0 + chunk * 8;
            int h = e >> 6, dh = e & 63;
            int s = (m0 & 2047) + tl;
            *(short8*)&dst[((b * 16 + h) * 2048 + s) * 64 + dh] =
                *(const short8*)&SMEM[tl * 136 + chunk * 8];
        }
    }
}

// ---------------------------------------------------------------------------
// Flash attention v5 on COMPACT tokens: 32x32x16 + 2-way split-K + half-width
// Ps. kb loop runs to nbp/128; key mask = (j < nb). No q-mask (all compact
// rows unmasked). Blocks beyond nbp exit. grid (16, 32), 512 thr.
// ---------------------------------------------------------------------------
__global__ __launch_bounds__(512, 4) void attn_kernel(
    const unsigned short* __restrict__ Qc, const unsigned short* __restrict__ Kc,
    const unsigned short* __restrict__ VTc, const int* __restrict__ hdr,
    unsigned short* __restrict__ Xattn)
{
    __shared__ __align__(16) unsigned short SMEM[26624];   // 53,248 B
    unsigned short* Ks = SMEM;
    unsigned short* Vs = SMEM + 8192;
    unsigned short* Ps = SMEM + 16384;
    float* mrg = (float*)SMEM;

    const int bh = blockIdx.y;
    const int b = bh >> 4;
    const int nbl = hdr[b], nbpl = hdr[2 + b];
    const int q0 = blockIdx.x * 128;
    if (q0 >= nbpl) return;

    const int t = threadIdx.x;
    const int lane = t & 63, w = t >> 6;
    const int l31 = lane & 31, half = lane >> 5;
    const int qg = w & 3, khalf = w >> 2;

    const unsigned short* Kp = Kc + (size_t)bh * 131072;
    const unsigned short* Vp = VTc + (size_t)bh * 131072;

    bf16x8 qf[4];
#pragma unroll
    for (int s = 0; s < 4; ++s)
        qf[s] = ld8(&Qc[(bh * 2048 + q0 + qg * 32 + l31) * 64 + s * 16 + half * 8]);

    short onev = (l31 == 0) ? (short)0x3F80 : (short)0;
    short8 ov = { onev, onev, onev, onev, onev, onev, onev, onev };
    bf16x8 ones_f = __builtin_bit_cast(bf16x8, ov);

    unsigned short* Pw = Ps + w * 1280;

    f32x16 accd[2], accl;
#pragma unroll
    for (int d = 0; d < 2; ++d)
#pragma unroll
        for (int r = 0; r < 16; ++r) accd[d][r] = 0.f;
#pragma unroll
    for (int r = 0; r < 16; ++r) accl[r] = 0.f;

    const int nkb = nbpl >> 7;
    for (int kb = 0; kb < nkb; ++kb) {
        const int k0 = kb * 128;
        __syncthreads();
#pragma unroll
        for (int ii = 0; ii < 2; ++ii) {
            int inst = w * 2 + ii;
            int row = inst * 8 + (lane >> 3);
            int cs = (lane & 7) ^ (row & 7);
            ldsdma16(&Ks[inst * 512], &Kp[(k0 + row) * 64 + cs * 8]);
        }
#pragma unroll
        for (int ii = 0; ii < 2; ++ii) {
            int inst = w * 2 + ii;
            int row = inst * 4 + (lane >> 4);
            int cs = (lane & 15) ^ (row & 15);
            ldsdma16(&Vs[inst * 512], &Vp[row * 2048 + k0 + cs * 8]);
        }
        float mc[2];
#pragma unroll
        for (int g = 0; g < 2; ++g)
            mc[g] = (k0 + khalf * 64 + g * 32 + l31 < nbl) ? 1.f : 0.f;
        __syncthreads();

#pragma unroll
        for (int g = 0; g < 2; ++g) {
            f32x16 z;
#pragma unroll
            for (int r = 0; r < 16; ++r) z[r] = 0.f;
            int rK = khalf * 64 + g * 32 + l31;
#pragma unroll
            for (int s = 0; s < 4; ++s) {
                int chunk = s * 2 + half;
                bf16x8 kf = ld8(&Ks[rK * 64 + ((chunk ^ (rK & 7)) << 3)]);
                z = __builtin_amdgcn_mfma_f32_32x32x16_bf16(qf[s], kf, z, 0, 0, 0);
            }
#pragma unroll
            for (int r = 0; r < 16; ++r) {
                float p = __expf(z[r]) * mc[g];
                int ql = (r & 3) + 8 * (r >> 2) + 4 * half;
                Pw[ql * 40 + l31] = f2bf_n(p);
            }
            bf16x8 pf[2];
#pragma unroll
            for (int sp = 0; sp < 2; ++sp)
                pf[sp] = ld8(&Pw[l31 * 40 + sp * 16 + half * 8]);
#pragma unroll
            for (int d = 0; d < 2; ++d) {
                int rV = d * 32 + l31;
#pragma unroll
                for (int sp = 0; sp < 2; ++sp) {
                    int chunk = khalf * 8 + g * 4 + sp * 2 + half;
                    bf16x8 vf = ld8(&Vs[rV * 128 + ((chunk ^ (rV & 15)) << 3)]);
                    accd[d] = __builtin_amdgcn_mfma_f32_32x32x16_bf16(
                        pf[sp], vf, accd[d], 0, 0, 0);
                }
            }
#pragma unroll
            for (int sp = 0; sp < 2; ++sp)
                accl = __builtin_amdgcn_mfma_f32_32x32x16_bf16(
                    pf[sp], ones_f, accl, 0, 0, 0);
        }
    }

    __syncthreads();
    if (khalf == 1) {
        float* q_ = mrg + qg * 3072;
#pragma unroll
        for (int r = 0; r < 16; ++r) {
            q_[(r) * 64 + lane]      = accd[0][r];
            q_[(16 + r) * 64 + lane] = accd[1][r];
            q_[(32 + r) * 64 + lane] = accl[r];
        }
    }
    __syncthreads();
    if (khalf == 0) {
        const float* q_ = mrg + qg * 3072;
#pragma unroll
        for (int r = 0; r < 16; ++r) {
            accd[0][r] += q_[(r) * 64 + lane];
            accd[1][r] += q_[(16 + r) * 64 + lane];
            accl[r]    += q_[(32 + r) * 64 + lane];
        }
#pragma unroll
        for (int r = 0; r < 16; ++r) {
            int ql = (r & 3) + 8 * (r >> 2) + 4 * half;
            int j = q0 + qg * 32 + ql;
            float lr = __shfl(accl[r], half * 32, 64);
            float inv = 1.f / (lr + 1e-13f);
#pragma unroll
            for (int d = 0; d < 2; ++d)
                Xattn[(b * 2048 + j) * 1024 + (bh & 15) * 64 + d * 32 + l31] =
                    f2bf_n(accd[d][r] * inv);
        }
    }
}

// ---------------------------------------------------------------------------
// Output projection on COMPACT rows, scatter to out via sidx. Blocks beyond
// nbp exit. grid (64, 8), 256 thr, 64x128 tiles, BK=64 DMA staging.
// ---------------------------------------------------------------------------
__global__ __launch_bounds__(256) void oproj_kernel(
    const unsigned short* __restrict__ A, const unsigned short* __restrict__ W,
    const float* __restrict__ bias, const int* __restrict__ sidx,
    const int* __restrict__ hdr, float* __restrict__ out)
{
    __shared__ __align__(16) unsigned short As[64 * 64];
    __shared__ __align__(16) unsigned short Bs[128 * 64];

    const int m0 = blockIdx.x * 64;
    const int b = m0 >> 11;
    const int nbl = hdr[b];
    if ((m0 & 2047) >= hdr[2 + b]) return;

    const int t = threadIdx.x;
    const int lane = t & 63, w = t >> 6;
    const int l15 = lane & 15, grp = lane >> 4;
    const int e0 = blockIdx.y * 128;
    const int srow = lane >> 3, sc_ = lane & 7;

    f32x4 acc[4][2];
#pragma unroll
    for (int i = 0; i < 4; ++i)
#pragma unroll
        for (int j = 0; j < 2; ++j) acc[i][j] = (f32x4){0.f, 0.f, 0.f, 0.f};

    for (int kt = 0; kt < 16; ++kt) {
        const int k0 = kt * 64;
        __syncthreads();
#pragma unroll
        for (int jj = 0; jj < 2; ++jj) {
            int chunk = w * 2 + jj;
            int row = chunk * 8 + srow;
            int cs = sc_ ^ (row & 7);
            ldsdma16(&As[chunk * 512], &A[(m0 + row) * 1024 + k0 + cs * 8]);
        }
#pragma unroll
        for (int jj = 0; jj < 4; ++jj) {
            int chunk = w * 4 + jj;
            int row = chunk * 8 + srow;
            int cs = sc_ ^ (row & 7);
            ldsdma16(&Bs[chunk * 512], &W[(e0 + row) * 1024 + k0 + cs * 8]);
        }
        __syncthreads();
#pragma unroll
        for (int kk = 0; kk < 64; kk += 32) {
            const int cb = kk >> 3;
            bf16x8 af[4], bfr[2];
#pragma unroll
            for (int i = 0; i < 4; ++i) {
                int r = i * 16 + l15;
                af[i] = ld8(&As[r * 64 + (((cb + grp) ^ (r & 7)) << 3)]);
            }
#pragma unroll
            for (int j = 0; j < 2; ++j) {
                int r = w * 32 + j * 16 + l15;
                bfr[j] = ld8(&Bs[r * 64 + (((cb + grp) ^ (r & 7)) << 3)]);
            }
#pragma unroll
            for (int i = 0; i < 4; ++i)
#pragma unroll
                for (int j = 0; j < 2; ++j)
                    acc[i][j] = __builtin_amdgcn_mfma_f32_16x16x32_bf16(
                        af[i], bfr[j], acc[i][j], 0, 0, 0);
        }
    }

#pragma unroll
    for (int j = 0; j < 2; ++j) {
        int e = e0 + w * 32 + j * 16 + l15;
        float bv_ = bias[e];
#pragma unroll
        for (int i = 0; i < 4; ++i)
#pragma unroll
            for (int r = 0; r < 4; ++r) {
                int jl = (m0 & 2047) + i * 16 + grp * 4 + r;
                if (jl < nbl) {
                    int s = sidx[b * 2048 + jl];
                    out[(size_t)(b * 2048 + s) * 1024 + e] = acc[i][j][r] + bv_;
                }
            }
    }
}

extern "C" void kernel_launch(void* const* d_in, const int* in_sizes, int n_in,
                              void* d_out, int out_size, void* d_ws, size_t ws_size,
                              hipStream_t stream) {
    const float* x    = (const float*)d_in[0];
    const float* mask = (const float*)d_in[1];
    const float* Wq   = (const float*)d_in[2];
    const float* bq   = (const float*)d_in[3];
    const float* Wk   = (const float*)d_in[4];
    const float* bk   = (const float*)d_in[5];
    const float* Wv   = (const float*)d_in[6];
    const float* bv   = (const float*)d_in[7];
    const float* Wo   = (const float*)d_in[8];
    const float* bo   = (const float*)d_in[9];
    float* out = (float*)d_out;

    unsigned short* Qc   = (unsigned short*)d_ws;    // u16 element offsets:
    unsigned short* Kc   = Qc + 4194304;
    unsigned short* VTc  = Qc + 8388608;
    unsigned short* XcXa = Qc + 12582912;            // Xc (gather->qkv), then Xattn (attn->oproj)
    unsigned short* Wb   = Qc + 16777216;
    int* sidx            = (int*)(Qc + 20971520);    // 4096 ints
    int* hdr             = sidx + 4096;              // nb[2], nbp[2]

    compact_kernel<<<dim3(2), 256, 0, stream>>>(mask, sidx, hdr);
    wconv_kernel<<<dim3(4096), 256, 0, stream>>>(Wq, Wk, Wv, Wo, Wb);
    gatherx_kernel<<<dim3(4096), 256, 0, stream>>>(x, sidx, hdr, XcXa);
    oinit_kernel<<<dim3(4096), 256, 0, stream>>>(bo, out);
    qkv_kernel<<<dim3(32, 24), 256, 0, stream>>>(XcXa, Wb, bq, bk, bv, hdr,
                                                 Qc, Kc, VTc);
    attn_kernel<<<dim3(16, 32), 512, 0, stream>>>(Qc, Kc, VTc, hdr, XcXa);
    oproj_kernel<<<dim3(64, 8), 256, 0, stream>>>(XcXa, Wb + 3145728, bo,
                                                  sidx, hdr, out);
}

// Round 16
// 178.465 us; speedup vs baseline: 1.8044x; 1.0303x over previous
//
#include <hip/hip_runtime.h>
#include <stdint.h>

#define DEV __device__ __forceinline__

typedef __attribute__((ext_vector_type(4))) float f32x4;
typedef __attribute__((ext_vector_type(16))) float f32x16;
typedef __attribute__((ext_vector_type(8))) __bf16 bf16x8;
typedef __attribute__((ext_vector_type(4))) __bf16 bf16x4;
typedef __attribute__((ext_vector_type(8))) short short8;
typedef __attribute__((ext_vector_type(4))) unsigned short u16x4;

DEV unsigned short f2bf_n(float f) {
    __bf16 h = (__bf16)f;
    return __builtin_bit_cast(unsigned short, h);
}
DEV bf16x8 ld8(const unsigned short* p) {
    short8 v = *(const short8*)p;
    return __builtin_bit_cast(bf16x8, v);
}
DEV void ldsdma16(unsigned short* lds, const unsigned short* g) {
    __builtin_amdgcn_global_load_lds(
        (const __attribute__((address_space(1))) unsigned int*)g,
        (__attribute__((address_space(3))) unsigned int*)lds, 16, 0, 0);
}

// ---------------------------------------------------------------------------
// Token compaction with parallel (Hillis-Steele) scan.
// sidx[b][j] = s of j-th unmasked token; hdr[b]=nb, hdr[2+b]=nbp (pad 128).
// ---------------------------------------------------------------------------
__global__ __launch_bounds__(256) void compact_kernel(
    const float* __restrict__ mask, int* __restrict__ sidx, int* __restrict__ hdr)
{
    __shared__ int part[256];
    const int b = blockIdx.x, t = threadIdx.x;
    int loc[8], cnt = 0;
#pragma unroll
    for (int k = 0; k < 8; ++k) {
        loc[k] = (mask[b * 2048 + t * 8 + k] > 0.5f) ? 1 : 0;
        cnt += loc[k];
    }
    part[t] = cnt;
    __syncthreads();
#pragma unroll
    for (int off = 1; off < 256; off <<= 1) {
        int v = (t >= off) ? part[t - off] : 0;
        __syncthreads();
        part[t] += v;
        __syncthreads();
    }
    const int total = part[255];
    if (t == 0) {
        hdr[b] = total;
        hdr[2 + b] = (total + 127) & ~127;
    }
    int base = part[t] - cnt;            // exclusive prefix
#pragma unroll
    for (int k = 0; k < 8; ++k)
        if (loc[k]) sidx[b * 2048 + (base++)] = t * 8 + k;
    for (int j = total + t; j < 2048; j += 256) sidx[b * 2048 + j] = -1;
}

// ---------------------------------------------------------------------------
// Fused prep: grid 12288 blocks x 256 thr, three block ranges co-scheduled:
//   [0,4096)     gather+convert X row -> compact Xc (zero pad rows)
//   [4096,8192)  out init: every token's out row = bo
//   [8192,12288) W f32 -> bf16 (Wq|Wk|Wv|Wo)
// ---------------------------------------------------------------------------
__global__ __launch_bounds__(256) void prep_kernel(
    const float* __restrict__ X, const float* __restrict__ mask_unused,
    const float* __restrict__ Wq, const float* __restrict__ Wk,
    const float* __restrict__ Wv, const float* __restrict__ Wo,
    const float* __restrict__ bo, const int* __restrict__ sidx,
    const int* __restrict__ hdr,
    unsigned short* __restrict__ Xc, unsigned short* __restrict__ Wb,
    float* __restrict__ out)
{
    const int bx = blockIdx.x, t = threadIdx.x;
    if (bx < 4096) {
        const int b = bx >> 11, j = bx & 2047;
        if (j >= hdr[2 + b]) return;
        const int col = t * 4;
        bf16x4 o;
        if (j < hdr[b]) {
            int s = sidx[b * 2048 + j];
            f32x4 v = *(const f32x4*)&X[(size_t)(b * 2048 + s) * 1024 + col];
            o = (bf16x4){ (__bf16)v[0], (__bf16)v[1], (__bf16)v[2], (__bf16)v[3] };
        } else {
            o = (bf16x4){ (__bf16)0.f, (__bf16)0.f, (__bf16)0.f, (__bf16)0.f };
        }
        *(bf16x4*)&Xc[(size_t)bx * 1024 + col] = o;
    } else if (bx < 8192) {
        int row = bx - 4096;
        int e = t * 4;
        f32x4 v = *(const f32x4*)&bo[e];
        *(f32x4*)&out[(size_t)row * 1024 + e] = v;
    } else {
        int c = (bx - 8192) * 256 + t;
        int wsel = c >> 18, off = (c & 262143) * 4;
        const float* ws_[4] = { Wq, Wk, Wv, Wo };
        f32x4 v = *(const f32x4*)(ws_[wsel] + off);
        bf16x4 b = { (__bf16)v[0], (__bf16)v[1], (__bf16)v[2], (__bf16)v[3] };
        *(bf16x4*)&Wb[wsel * 1048576 + off] = b;
    }
}

// ---------------------------------------------------------------------------
// Fused QKV projection on COMPACT rows (256 thr, BK=64 single-buffer DMA
// staging). Blocks beyond nbp(b) exit. grid (32, 24). [UNCHANGED]
// ---------------------------------------------------------------------------
__global__ __launch_bounds__(256) void qkv_kernel(
    const unsigned short* __restrict__ Xc, const unsigned short* __restrict__ Wb,
    const float* __restrict__ bq, const float* __restrict__ bk,
    const float* __restrict__ bv, const int* __restrict__ hdr,
    unsigned short* __restrict__ Qc, unsigned short* __restrict__ Kc,
    unsigned short* __restrict__ VTc)
{
    __shared__ __align__(16) unsigned short SMEM[17408];
    unsigned short* As = SMEM;
    unsigned short* Bs = SMEM + 8192;

    const int m0 = blockIdx.x * 128;
    const int b = m0 >> 11;
    if ((m0 & 2047) >= hdr[2 + b]) return;

    const int t = threadIdx.x;
    const int lane = t & 63, w = t >> 6;
    const int wm = w & 1, wn = w >> 1;
    const int l15 = lane & 15, grp = lane >> 4;
    const int which = blockIdx.y >> 3;
    const int e0 = (blockIdx.y & 7) * 128;

    const unsigned short* Wmat = Wb + which * 1048576;
    const float* bias = (which == 0) ? bq : (which == 1) ? bk : bv;

    const int srow = lane >> 3, sc_ = lane & 7;

    f32x4 acc[4][4];
#pragma unroll
    for (int i = 0; i < 4; ++i)
#pragma unroll
        for (int j = 0; j < 4; ++j) acc[i][j] = (f32x4){0.f, 0.f, 0.f, 0.f};

    for (int kt = 0; kt < 16; ++kt) {
        const int k0 = kt * 64;
        __syncthreads();
#pragma unroll
        for (int j = 0; j < 4; ++j) {
            int row = (w * 4 + j) * 8 + srow;
            int cs = sc_ ^ (row & 7);
            ldsdma16(&As[(w * 4 + j) * 512],
                     &Xc[(m0 + row) * 1024 + k0 + cs * 8]);
            ldsdma16(&Bs[(w * 4 + j) * 512],
                     &Wmat[(e0 + row) * 1024 + k0 + cs * 8]);
        }
        __syncthreads();
#pragma unroll
        for (int kk = 0; kk < 64; kk += 32) {
            const int cb = kk >> 3;
            bf16x8 af[4], bfr[4];
#pragma unroll
            for (int i = 0; i < 4; ++i) {
                int r = wm * 64 + i * 16 + l15;
                af[i] = ld8(&As[r * 64 + (((cb + grp) ^ (r & 7)) << 3)]);
            }
#pragma unroll
            for (int j = 0; j < 4; ++j) {
                int r = wn * 64 + j * 16 + l15;
                bfr[j] = ld8(&Bs[r * 64 + (((cb + grp) ^ (r & 7)) << 3)]);
            }
#pragma unroll
            for (int i = 0; i < 4; ++i)
#pragma unroll
                for (int j = 0; j < 4; ++j)
                    acc[i][j] = __builtin_amdgcn_mfma_f32_16x16x32_bf16(
                        af[i], bfr[j], acc[i][j], 0, 0, 0);
        }
    }

    __syncthreads();

    if (which == 2) {
#pragma unroll
        for (int j = 0; j < 4; ++j) {
            int e = e0 + wn * 64 + j * 16 + l15;
            float bv_ = bias[e];
#pragma unroll
            for (int i = 0; i < 4; ++i) {
                u16x4 pk;
#pragma unroll
                for (int r = 0; r < 4; ++r) pk[r] = f2bf_n(acc[i][j][r] + bv_);
                *(u16x4*)&SMEM[(wn * 64 + j * 16 + l15) * 136 +
                               wm * 64 + i * 16 + grp * 4] = pk;
            }
        }
        __syncthreads();
        const int s0 = m0 & 2047;
#pragma unroll
        for (int round = 0; round < 8; ++round) {
            int dhl = (t >> 4) + round * 16;
            int chunk = t & 15;
            int h = (e0 + dhl) >> 6, dh = (e0 + dhl) & 63;
            *(short8*)&VTc[((b * 16 + h) * 64 + dh) * 2048 + s0 + chunk * 8] =
                *(const short8*)&SMEM[dhl * 136 + chunk * 8];
        }
    } else {
        const float scale = (which == 0) ? 0.125f : 1.0f;
#pragma unroll
        for (int j = 0; j < 4; ++j) {
            int e = e0 + wn * 64 + j * 16 + l15;
            float bv_ = bias[e];
#pragma unroll
            for (int i = 0; i < 4; ++i)
#pragma unroll
                for (int r = 0; r < 4; ++r)
                    SMEM[(wm * 64 + i * 16 + grp * 4 + r) * 136 +
                         wn * 64 + j * 16 + l15] =
                        f2bf_n((acc[i][j][r] + bv_) * scale);
        }
        __syncthreads();
        unsigned short* dst = (which == 0) ? Qc : Kc;
#pragma unroll
        for (int round = 0; round < 8; ++round) {
            int tl = (t >> 4) + round * 16;
            int chunk = t & 15;
            int e = e0 + chunk * 8;
            int h = e >> 6, dh = e & 63;
            int s = (m0 & 2047) + tl;
            *(short8*)&dst[((b * 16 + h) * 2048 + s) * 64 + dh] =
                *(const short8*)&SMEM[tl * 136 + chunk * 8];
        }
    }
}

// ---------------------------------------------------------------------------
// Flash attention v5 on COMPACT tokens (32x32x16 + 2-way split-K + half-width
// Ps). kb loop to nbp/128; key mask = (j < nb). grid (16, 32). [UNCHANGED]
// ---------------------------------------------------------------------------
__global__ __launch_bounds__(512, 4) void attn_kernel(
    const unsigned short* __restrict__ Qc, const unsigned short* __restrict__ Kc,
    const unsigned short* __restrict__ VTc, const int* __restrict__ hdr,
    unsigned short* __restrict__ Xattn)
{
    __shared__ __align__(16) unsigned short SMEM[26624];   // 53,248 B
    unsigned short* Ks = SMEM;
    unsigned short* Vs = SMEM + 8192;
    unsigned short* Ps = SMEM + 16384;
    float* mrg = (float*)SMEM;

    const int bh = blockIdx.y;
    const int b = bh >> 4;
    const int nbl = hdr[b], nbpl = hdr[2 + b];
    const int q0 = blockIdx.x * 128;
    if (q0 >= nbpl) return;

    const int t = threadIdx.x;
    const int lane = t & 63, w = t >> 6;
    const int l31 = lane & 31, half = lane >> 5;
    const int qg = w & 3, khalf = w >> 2;

    const unsigned short* Kp = Kc + (size_t)bh * 131072;
    const unsigned short* Vp = VTc + (size_t)bh * 131072;

    bf16x8 qf[4];
#pragma unroll
    for (int s = 0; s < 4; ++s)
        qf[s] = ld8(&Qc[(bh * 2048 + q0 + qg * 32 + l31) * 64 + s * 16 + half * 8]);

    short onev = (l31 == 0) ? (short)0x3F80 : (short)0;
    short8 ov = { onev, onev, onev, onev, onev, onev, onev, onev };
    bf16x8 ones_f = __builtin_bit_cast(bf16x8, ov);

    unsigned short* Pw = Ps + w * 1280;

    f32x16 accd[2], accl;
#pragma unroll
    for (int d = 0; d < 2; ++d)
#pragma unroll
        for (int r = 0; r < 16; ++r) accd[d][r] = 0.f;
#pragma unroll
    for (int r = 0; r < 16; ++r) accl[r] = 0.f;

    const int nkb = nbpl >> 7;
    for (int kb = 0; kb < nkb; ++kb) {
        const int k0 = kb * 128;
        __syncthreads();
#pragma unroll
        for (int ii = 0; ii < 2; ++ii) {
            int inst = w * 2 + ii;
            int row = inst * 8 + (lane >> 3);
            int cs = (lane & 7) ^ (row & 7);
            ldsdma16(&Ks[inst * 512], &Kp[(k0 + row) * 64 + cs * 8]);
        }
#pragma unroll
        for (int ii = 0; ii < 2; ++ii) {
            int inst = w * 2 + ii;
            int row = inst * 4 + (lane >> 4);
            int cs = (lane & 15) ^ (row & 15);
            ldsdma16(&Vs[inst * 512], &Vp[row * 2048 + k0 + cs * 8]);
        }
        float mc[2];
#pragma unroll
        for (int g = 0; g < 2; ++g)
            mc[g] = (k0 + khalf * 64 + g * 32 + l31 < nbl) ? 1.f : 0.f;
        __syncthreads();

#pragma unroll
        for (int g = 0; g < 2; ++g) {
            f32x16 z;
#pragma unroll
            for (int r = 0; r < 16; ++r) z[r] = 0.f;
            int rK = khalf * 64 + g * 32 + l31;
#pragma unroll
            for (int s = 0; s < 4; ++s) {
                int chunk = s * 2 + half;
                bf16x8 kf = ld8(&Ks[rK * 64 + ((chunk ^ (rK & 7)) << 3)]);
                z = __builtin_amdgcn_mfma_f32_32x32x16_bf16(qf[s], kf, z, 0, 0, 0);
            }
#pragma unroll
            for (int r = 0; r < 16; ++r) {
                float p = __expf(z[r]) * mc[g];
                int ql = (r & 3) + 8 * (r >> 2) + 4 * half;
                Pw[ql * 40 + l31] = f2bf_n(p);
            }
            bf16x8 pf[2];
#pragma unroll
            for (int sp = 0; sp < 2; ++sp)
                pf[sp] = ld8(&Pw[l31 * 40 + sp * 16 + half * 8]);
#pragma unroll
            for (int d = 0; d < 2; ++d) {
                int rV = d * 32 + l31;
#pragma unroll
                for (int sp = 0; sp < 2; ++sp) {
                    int chunk = khalf * 8 + g * 4 + sp * 2 + half;
                    bf16x8 vf = ld8(&Vs[rV * 128 + ((chunk ^ (rV & 15)) << 3)]);
                    accd[d] = __builtin_amdgcn_mfma_f32_32x32x16_bf16(
                        pf[sp], vf, accd[d], 0, 0, 0);
                }
            }
#pragma unroll
            for (int sp = 0; sp < 2; ++sp)
                accl = __builtin_amdgcn_mfma_f32_32x32x16_bf16(
                    pf[sp], ones_f, accl, 0, 0, 0);
        }
    }

    __syncthreads();
    if (khalf == 1) {
        float* q_ = mrg + qg * 3072;
#pragma unroll
        for (int r = 0; r < 16; ++r) {
            q_[(r) * 64 + lane]      = accd[0][r];
            q_[(16 + r) * 64 + lane] = accd[1][r];
            q_[(32 + r) * 64 + lane] = accl[r];
        }
    }
    __syncthreads();
    if (khalf == 0) {
        const float* q_ = mrg + qg * 3072;
#pragma unroll
        for (int r = 0; r < 16; ++r) {
            accd[0][r] += q_[(r) * 64 + lane];
            accd[1][r] += q_[(16 + r) * 64 + lane];
            accl[r]    += q_[(32 + r) * 64 + lane];
        }
#pragma unroll
        for (int r = 0; r < 16; ++r) {
            int ql = (r & 3) + 8 * (r >> 2) + 4 * half;
            int j = q0 + qg * 32 + ql;
            float lr = __shfl(accl[r], half * 32, 64);
            float inv = 1.f / (lr + 1e-13f);
#pragma unroll
            for (int d = 0; d < 2; ++d)
                Xattn[(b * 2048 + j) * 1024 + (bh & 15) * 64 + d * 32 + l31] =
                    f2bf_n(accd[d][r] * inv);
        }
    }
}

// ---------------------------------------------------------------------------
// Output projection on COMPACT rows, scatter via sidx. grid (64, 8).
// [UNCHANGED]
// ---------------------------------------------------------------------------
__global__ __launch_bounds__(256) void oproj_kernel(
    const unsigned short* __restrict__ A, const unsigned short* __restrict__ W,
    const float* __restrict__ bias, const int* __restrict__ sidx,
    const int* __restrict__ hdr, float* __restrict__ out)
{
    __shared__ __align__(16) unsigned short As[64 * 64];
    __shared__ __align__(16) unsigned short Bs[128 * 64];

    const int m0 = blockIdx.x * 64;
    const int b = m0 >> 11;
    const int nbl = hdr[b];
    if ((m0 & 2047) >= hdr[2 + b]) return;

    const int t = threadIdx.x;
    const int lane = t & 63, w = t >> 6;
    const int l15 = lane & 15, grp = lane >> 4;
    const int e0 = blockIdx.y * 128;
    const int srow = lane >> 3, sc_ = lane & 7;

    f32x4 acc[4][2];
#pragma unroll
    for (int i = 0; i < 4; ++i)
#pragma unroll
        for (int j = 0; j < 2; ++j) acc[i][j] = (f32x4){0.f, 0.f, 0.f, 0.f};

    for (int kt = 0; kt < 16; ++kt) {
        const int k0 = kt * 64;
        __syncthreads();
#pragma unroll
        for (int jj = 0; jj < 2; ++jj) {
            int chunk = w * 2 + jj;
            int row = chunk * 8 + srow;
            int cs = sc_ ^ (row & 7);
            ldsdma16(&As[chunk * 512], &A[(m0 + row) * 1024 + k0 + cs * 8]);
        }
#pragma unroll
        for (int jj = 0; jj < 4; ++jj) {
            int chunk = w * 4 + jj;
            int row = chunk * 8 + srow;
            int cs = sc_ ^ (row & 7);
            ldsdma16(&Bs[chunk * 512], &W[(e0 + row) * 1024 + k0 + cs * 8]);
        }
        __syncthreads();
#pragma unroll
        for (int kk = 0; kk < 64; kk += 32) {
            const int cb = kk >> 3;
            bf16x8 af[4], bfr[2];
#pragma unroll
            for (int i = 0; i < 4; ++i) {
                int r = i * 16 + l15;
                af[i] = ld8(&As[r * 64 + (((cb + grp) ^ (r & 7)) << 3)]);
            }
#pragma unroll
            for (int j = 0; j < 2; ++j) {
                int r = w * 32 + j * 16 + l15;
                bfr[j] = ld8(&Bs[r * 64 + (((cb + grp) ^ (r & 7)) << 3)]);
            }
#pragma unroll
            for (int i = 0; i < 4; ++i)
#pragma unroll
                for (int j = 0; j < 2; ++j)
                    acc[i][j] = __builtin_amdgcn_mfma_f32_16x16x32_bf16(
                        af[i], bfr[j], acc[i][j], 0, 0, 0);
        }
    }

#pragma unroll
    for (int j = 0; j < 2; ++j) {
        int e = e0 + w * 32 + j * 16 + l15;
        float bv_ = bias[e];
#pragma unroll
        for (int i = 0; i < 4; ++i)
#pragma unroll
            for (int r = 0; r < 4; ++r) {
                int jl = (m0 & 2047) + i * 16 + grp * 4 + r;
                if (jl < nbl) {
                    int s = sidx[b * 2048 + jl];
                    out[(size_t)(b * 2048 + s) * 1024 + e] = acc[i][j][r] + bv_;
                }
            }
    }
}

extern "C" void kernel_launch(void* const* d_in, const int* in_sizes, int n_in,
                              void* d_out, int out_size, void* d_ws, size_t ws_size,
                              hipStream_t stream) {
    const float* x    = (const float*)d_in[0];
    const float* mask = (const float*)d_in[1];
    const float* Wq   = (const float*)d_in[2];
    const float* bq   = (const float*)d_in[3];
    const float* Wk   = (const float*)d_in[4];
    const float* bk   = (const float*)d_in[5];
    const float* Wv   = (const float*)d_in[6];
    const float* bv   = (const float*)d_in[7];
    const float* Wo   = (const float*)d_in[8];
    const float* bo   = (const float*)d_in[9];
    float* out = (float*)d_out;

    unsigned short* Qc   = (unsigned short*)d_ws;    // u16 element offsets:
    unsigned short* Kc   = Qc + 4194304;
    unsigned short* VTc  = Qc + 8388608;
    unsigned short* XcXa = Qc + 12582912;            // Xc (prep->qkv), then Xattn
    unsigned short* Wb   = Qc + 16777216;
    int* sidx            = (int*)(Qc + 20971520);    // 4096 ints
    int* hdr             = sidx + 4096;              // nb[2], nbp[2]

    compact_kernel<<<dim3(2), 256, 0, stream>>>(mask, sidx, hdr);
    prep_kernel<<<dim3(12288), 256, 0, stream>>>(x, mask, Wq, Wk, Wv, Wo, bo,
                                                 sidx, hdr, XcXa, Wb, out);
    qkv_kernel<<<dim3(32, 24), 256, 0, stream>>>(XcXa, Wb, bq, bk, bv, hdr,
                                                 Qc, Kc, VTc);
    attn_kernel<<<dim3(16, 32), 512, 0, stream>>>(Qc, Kc, VTc, hdr, XcXa);
    oproj_kernel<<<dim3(64, 8), 256, 0, stream>>>(XcXa, Wb + 3145728, bo,
                                                  sidx, hdr, out);
}